// Round 1
// baseline (498.732 us; speedup 1.0000x reference)
//
#include <hip/hip_runtime.h>

typedef unsigned short u16;
typedef unsigned int u32;
typedef __attribute__((ext_vector_type(8))) short short8;
typedef __attribute__((ext_vector_type(4))) float f32x4;
typedef __attribute__((ext_vector_type(4))) u16 u16x4;

#define QK_SCALE 0.12751736915185197f  // log2(e)/sqrt(128)

__device__ __forceinline__ u16 f2bf(float f) {
  u32 u = __builtin_bit_cast(u32, f);
  u = u + 0x7FFFu + ((u >> 16) & 1u);
  return (u16)(u >> 16);
}

__device__ __forceinline__ void async_copy16(const void* g, void* l) {
  __builtin_amdgcn_global_load_lds(
      (const __attribute__((address_space(1))) u32*)g,
      (__attribute__((address_space(3))) u32*)l, 16, 0, 0);
}

// ---------------- cast x (fp32 -> bf16) ----------------
__global__ __launch_bounds__(256) void cast_x_kernel(const float* __restrict__ x,
                                                     u16* __restrict__ xb, int n) {
  int i = (blockIdx.x * 256 + threadIdx.x) * 8;
  if (i >= n) return;
  float4 a = *(const float4*)(x + i);
  float4 b = *(const float4*)(x + i + 4);
  short8 o;
  o[0] = (short)f2bf(a.x); o[1] = (short)f2bf(a.y);
  o[2] = (short)f2bf(a.z); o[3] = (short)f2bf(a.w);
  o[4] = (short)f2bf(b.x); o[5] = (short)f2bf(b.y);
  o[6] = (short)f2bf(b.z); o[7] = (short)f2bf(b.w);
  *(short8*)(xb + i) = o;
}

// ---------------- transpose+cast W (fp32 [k][n] -> bf16 WT [n][k]) ----------------
__global__ __launch_bounds__(256) void transW_kernel(
    const float* __restrict__ W0, const float* __restrict__ W1,
    const float* __restrict__ W2, const float* __restrict__ W3,
    u16* __restrict__ O0, u16* __restrict__ O1, u16* __restrict__ O2, u16* __restrict__ O3) {
  const float* Ws[4] = {W0, W1, W2, W3};
  u16* Os[4] = {O0, O1, O2, O3};
  const float* W = Ws[blockIdx.z];
  u16* O = Os[blockIdx.z];

  __shared__ float T[64][65];
  int t = threadIdx.x;
  int k0 = blockIdx.y * 64, n0 = blockIdx.x * 64;
  int r = t >> 4, c = (t & 15) * 4;
#pragma unroll
  for (int i = 0; i < 4; ++i) {
    float4 v = *(const float4*)&W[(size_t)(k0 + r + i * 16) * 2048 + n0 + c];
    T[r + i * 16][c + 0] = v.x; T[r + i * 16][c + 1] = v.y;
    T[r + i * 16][c + 2] = v.z; T[r + i * 16][c + 3] = v.w;
  }
  __syncthreads();
#pragma unroll
  for (int i = 0; i < 4; ++i) {
    int nn = r + i * 16;
    u16x4 o;
    o[0] = f2bf(T[c + 0][nn]); o[1] = f2bf(T[c + 1][nn]);
    o[2] = f2bf(T[c + 2][nn]); o[3] = f2bf(T[c + 3][nn]);
    *(u16x4*)&O[(size_t)(n0 + nn) * 2048 + k0 + c] = o;
  }
}

// ---------------- GEMM: C(4096x2048) = A(4096x2048) * WT^T + bias ----------------
// MODE 0: three matrices (z=0,1,2) -> Q/K/V bf16 in (b,h,n,dk) layout
// MODE 1: one matrix -> fp32 d_out row-major
template <int MODE>
__global__ __launch_bounds__(256, 2) void gemm128_kernel(
    const u16* __restrict__ A,
    const u16* __restrict__ W0, const u16* __restrict__ W1, const u16* __restrict__ W2,
    const float* __restrict__ b0, const float* __restrict__ b1, const float* __restrict__ b2,
    u16* __restrict__ oq, u16* __restrict__ ok, u16* __restrict__ ov,
    float* __restrict__ of) {
  const u16* W;
  const float* bias;
  u16* outb = nullptr;
  if (MODE == 0) {
    int z = blockIdx.z;
    W = (z == 0) ? W0 : (z == 1) ? W1 : W2;
    bias = (z == 0) ? b0 : (z == 1) ? b1 : b2;
    outb = (z == 0) ? oq : (z == 1) ? ok : ov;
  } else {
    W = W0;
    bias = b0;
  }

  __shared__ __align__(16) u16 As[128 * 32];
  __shared__ __align__(16) u16 Bs[128 * 32];

  int t = threadIdx.x;
  int lane = t & 63, w = t >> 6;
  int wm = w >> 1, wn = w & 1;
  int g = lane >> 4, lr = lane & 15;
  int m0 = blockIdx.y * 128, n0 = blockIdx.x * 128;

  f32x4 acc[4][4] = {};

  for (int kt = 0; kt < 2048; kt += 32) {
#pragma unroll
    for (int rr = 0; rr < 2; ++rr) {
      int p = t + rr * 256;          // 16B chunk index 0..511
      int row = p >> 2;              // tile row (64B rows, 4 chunks)
      int cs = (p & 3) ^ (row & 3);  // pre-swizzled source chunk
      async_copy16(A + (size_t)(m0 + row) * 2048 + kt + cs * 8, (void*)(As + p * 8));
      async_copy16(W + (size_t)(n0 + row) * 2048 + kt + cs * 8, (void*)(Bs + p * 8));
    }
    __syncthreads();

    short8 af[4], bf[4];
#pragma unroll
    for (int mf = 0; mf < 4; ++mf) {
      int row = wm * 64 + mf * 16 + lr;
      int kc = g ^ (row & 3);
      af[mf] = *(const short8*)&As[row * 32 + kc * 8];
    }
#pragma unroll
    for (int nf = 0; nf < 4; ++nf) {
      int row = wn * 64 + nf * 16 + lr;
      int kc = g ^ (row & 3);
      bf[nf] = *(const short8*)&Bs[row * 32 + kc * 8];
    }
#pragma unroll
    for (int mf = 0; mf < 4; ++mf)
#pragma unroll
      for (int nf = 0; nf < 4; ++nf)
        acc[mf][nf] = __builtin_amdgcn_mfma_f32_16x16x32_bf16(af[mf], bf[nf], acc[mf][nf], 0, 0, 0);
    __syncthreads();
  }

#pragma unroll
  for (int mf = 0; mf < 4; ++mf) {
#pragma unroll
    for (int nf = 0; nf < 4; ++nf) {
      int col = n0 + wn * 64 + nf * 16 + lr;
      float bv = bias[col];
#pragma unroll
      for (int i = 0; i < 4; ++i) {
        int rr = m0 + wm * 64 + mf * 16 + 4 * g + i;
        float v = acc[mf][nf][i] + bv;
        if (MODE == 0) {
          int b = rr >> 11, np = rr & 2047, h = col >> 7, dk = col & 127;
          outb[((size_t)(b * 16 + h) * 2048 + np) * 128 + dk] = f2bf(v);
        } else {
          of[(size_t)rr * 2048 + col] = v;
        }
      }
    }
  }
}

// ---------------- causal flash attention ----------------
// grid: (32 q-tiles reversed, 32 bh). block: 256 (4 waves x 16 q-rows).
__global__ __launch_bounds__(256, 2) void attn_kernel(
    const u16* __restrict__ Q, const u16* __restrict__ K, const u16* __restrict__ V,
    u16* __restrict__ ctx) {
  int bh = blockIdx.y;
  int q0 = (int)(gridDim.x - 1 - blockIdx.x) * 64;
  int t = threadIdx.x, lane = t & 63, w = t >> 6;
  int g = lane >> 4, lr = lane & 15;

  const u16* Qb = Q + (size_t)bh * 2048 * 128;
  const u16* Kb = K + (size_t)bh * 2048 * 128;
  const u16* Vb = V + (size_t)bh * 2048 * 128;

  __shared__ __align__(16) u16 Ks[32 * 128];    // xor-swizzled rows
  __shared__ __align__(16) u16 Vt[128 * 40];    // transposed, padded
  __shared__ __align__(16) u16 Ps[4 * 16 * 40]; // per-wave P, padded

  // hoist Q fragments (16 q-rows per wave)
  int qrow = q0 + w * 16 + lr;
  short8 qf[4];
#pragma unroll
  for (int kb = 0; kb < 4; ++kb)
    qf[kb] = *(const short8*)(Qb + (size_t)qrow * 128 + kb * 32 + g * 8);

  float m2[4], lsum[4];
  f32x4 acc[8] = {};
#pragma unroll
  for (int i = 0; i < 4; ++i) { m2[i] = -1e30f; lsum[i] = 0.f; }

  int wave_max_row = q0 + w * 16 + 15;
  int kv_end = q0 + 64;

  for (int kv0 = 0; kv0 < kv_end; kv0 += 32) {
    // stage K via global_load_lds, source pre-swizzled (chunk ^= row&7)
#pragma unroll
    for (int rr = 0; rr < 2; ++rr) {
      int p = t + rr * 256;  // 512 chunks, 16 per row
      int row = p >> 4;
      int cs = (p & 15) ^ (row & 7);
      async_copy16(Kb + (size_t)(kv0 + row) * 128 + cs * 8, (void*)(Ks + p * 8));
    }
    // stage V transposed (reg -> LDS scalar writes)
    {
      int vr = t >> 3, dk0 = (t & 7) * 16;
      const u16* src = Vb + (size_t)(kv0 + vr) * 128 + dk0;
      short8 v0 = *(const short8*)src;
      short8 v1 = *(const short8*)(src + 8);
#pragma unroll
      for (int j = 0; j < 8; ++j) Vt[(dk0 + j) * 40 + vr] = (u16)v0[j];
#pragma unroll
      for (int j = 0; j < 8; ++j) Vt[(dk0 + 8 + j) * 40 + vr] = (u16)v1[j];
    }
    __syncthreads();

    if (kv0 <= wave_max_row) {  // wave-uniform causal skip
      // QK^T
      f32x4 sf[2] = {};
#pragma unroll
      for (int sb = 0; sb < 2; ++sb) {
#pragma unroll
        for (int kb = 0; kb < 4; ++kb) {
          int krow = 16 * sb + lr;
          int cc = (kb * 4 + g) ^ (krow & 7);
          short8 kf = *(const short8*)&Ks[krow * 128 + cc * 8];
          sf[sb] = __builtin_amdgcn_mfma_f32_16x16x32_bf16(qf[kb], kf, sf[sb], 0, 0, 0);
        }
      }

      // online softmax (exp2 domain), 4 q-rows per lane
      float p0v[4], p1v[4];
#pragma unroll
      for (int i = 0; i < 4; ++i) {
        int row = q0 + w * 16 + 4 * g + i;
        float s0 = sf[0][i] * QK_SCALE;
        float s1 = sf[1][i] * QK_SCALE;
        if (kv0 + lr > row) s0 = -1e30f;
        if (kv0 + 16 + lr > row) s1 = -1e30f;
        float tmax = fmaxf(s0, s1);
        tmax = fmaxf(tmax, __shfl_xor(tmax, 1));
        tmax = fmaxf(tmax, __shfl_xor(tmax, 2));
        tmax = fmaxf(tmax, __shfl_xor(tmax, 4));
        tmax = fmaxf(tmax, __shfl_xor(tmax, 8));
        float mn = fmaxf(m2[i], tmax);
        float r = exp2f(m2[i] - mn);
        m2[i] = mn;
        float p0 = exp2f(s0 - mn), p1 = exp2f(s1 - mn);
        float rs = p0 + p1;
        rs += __shfl_xor(rs, 1);
        rs += __shfl_xor(rs, 2);
        rs += __shfl_xor(rs, 4);
        rs += __shfl_xor(rs, 8);
        lsum[i] = lsum[i] * r + rs;
#pragma unroll
        for (int nb = 0; nb < 8; ++nb) acc[nb][i] *= r;
        p0v[i] = p0; p1v[i] = p1;
      }

      // P -> per-wave LDS (A-frag layout round trip)
      u16* Pw = Ps + w * 16 * 40;
#pragma unroll
      for (int i = 0; i < 4; ++i) {
        Pw[(4 * g + i) * 40 + lr] = f2bf(p0v[i]);
        Pw[(4 * g + i) * 40 + lr + 16] = f2bf(p1v[i]);
      }

      short8 pf = *(const short8*)&Pw[lr * 40 + 8 * g];
#pragma unroll
      for (int nb = 0; nb < 8; ++nb) {
        short8 vf = *(const short8*)&Vt[(16 * nb + lr) * 40 + 8 * g];
        acc[nb] = __builtin_amdgcn_mfma_f32_16x16x32_bf16(pf, vf, acc[nb], 0, 0, 0);
      }
    }
    __syncthreads();
  }

  // epilogue: normalize and store context bf16 (b, n, h*128+dk)
  int b = bh >> 4, h = bh & 15;
#pragma unroll
  for (int i = 0; i < 4; ++i) {
    int row = q0 + w * 16 + 4 * g + i;
    float inv = 1.f / lsum[i];
    u16* dst = ctx + ((size_t)(b * 2048 + row)) * 2048 + h * 128;
#pragma unroll
    for (int nb = 0; nb < 8; ++nb) dst[16 * nb + lr] = f2bf(acc[nb][i] * inv);
  }
}

// ---------------- launcher ----------------
extern "C" void kernel_launch(void* const* d_in, const int* in_sizes, int n_in,
                              void* d_out, int out_size, void* d_ws, size_t ws_size,
                              hipStream_t stream) {
  const float* x = (const float*)d_in[0];
  const float* Wq = (const float*)d_in[1];
  const float* bq = (const float*)d_in[2];
  const float* Wk = (const float*)d_in[3];
  const float* bk = (const float*)d_in[4];
  const float* Wv = (const float*)d_in[5];
  const float* bv = (const float*)d_in[6];
  const float* Wo = (const float*)d_in[7];
  const float* bo = (const float*)d_in[8];
  float* out = (float*)d_out;

  u16* xb = (u16*)d_ws;               // 4096x2048 bf16
  u16* WTq = xb + 8388608;            // each 2048x2048 bf16
  u16* WTk = WTq + 4194304;
  u16* WTv = WTk + 4194304;
  u16* WTo = WTv + 4194304;
  u16* Qs = WTo + 4194304;            // (b,h,n,dk) bf16
  u16* Ks = Qs + 8388608;
  u16* Vs = Ks + 8388608;
  u16* ctx = Vs + 8388608;            // (b,n,d) bf16

  cast_x_kernel<<<4096, 256, 0, stream>>>(x, xb, 8388608);
  transW_kernel<<<dim3(32, 32, 4), 256, 0, stream>>>(Wq, Wk, Wv, Wo, WTq, WTk, WTv, WTo);
  gemm128_kernel<0><<<dim3(16, 32, 3), 256, 0, stream>>>(
      xb, WTq, WTk, WTv, bq, bk, bv, Qs, Ks, Vs, nullptr);
  attn_kernel<<<dim3(32, 32), 256, 0, stream>>>(Qs, Ks, Vs, ctx);
  gemm128_kernel<1><<<dim3(16, 32, 1), 256, 0, stream>>>(
      ctx, WTo, nullptr, nullptr, bo, nullptr, nullptr, nullptr, nullptr, nullptr, out);
}

// Round 2
// 368.065 us; speedup vs baseline: 1.3550x; 1.3550x over previous
//
#include <hip/hip_runtime.h>

typedef unsigned short u16;
typedef unsigned int u32;
typedef __attribute__((ext_vector_type(8))) short short8;
typedef __attribute__((ext_vector_type(4))) float f32x4;
typedef __attribute__((ext_vector_type(4))) u16 u16x4;

#define QK_SCALE 0.12751736915185197f  // log2(e)/sqrt(128)

__device__ __forceinline__ u16 f2bf(float f) {
  u32 u = __builtin_bit_cast(u32, f);
  u = u + 0x7FFFu + ((u >> 16) & 1u);
  return (u16)(u >> 16);
}

__device__ __forceinline__ void async_copy16(const void* g, void* l) {
  __builtin_amdgcn_global_load_lds(
      (const __attribute__((address_space(1))) u32*)g,
      (__attribute__((address_space(3))) u32*)l, 16, 0, 0);
}

// ---------------- cast x (fp32 -> bf16) ----------------
__global__ __launch_bounds__(256) void cast_x_kernel(const float* __restrict__ x,
                                                     u16* __restrict__ xb, int n) {
  int i = (blockIdx.x * 256 + threadIdx.x) * 8;
  if (i >= n) return;
  float4 a = *(const float4*)(x + i);
  float4 b = *(const float4*)(x + i + 4);
  short8 o;
  o[0] = (short)f2bf(a.x); o[1] = (short)f2bf(a.y);
  o[2] = (short)f2bf(a.z); o[3] = (short)f2bf(a.w);
  o[4] = (short)f2bf(b.x); o[5] = (short)f2bf(b.y);
  o[6] = (short)f2bf(b.z); o[7] = (short)f2bf(b.w);
  *(short8*)(xb + i) = o;
}

// ---------------- transpose+cast W (fp32 [k][n] -> bf16 WT [n][k]) ----------------
__global__ __launch_bounds__(256) void transW_kernel(
    const float* __restrict__ W0, const float* __restrict__ W1,
    const float* __restrict__ W2, const float* __restrict__ W3,
    u16* __restrict__ O0, u16* __restrict__ O1, u16* __restrict__ O2, u16* __restrict__ O3) {
  const float* Ws[4] = {W0, W1, W2, W3};
  u16* Os[4] = {O0, O1, O2, O3};
  const float* W = Ws[blockIdx.z];
  u16* O = Os[blockIdx.z];

  __shared__ float T[64][65];
  int t = threadIdx.x;
  int k0 = blockIdx.y * 64, n0 = blockIdx.x * 64;
  int r = t >> 4, c = (t & 15) * 4;
#pragma unroll
  for (int i = 0; i < 4; ++i) {
    float4 v = *(const float4*)&W[(size_t)(k0 + r + i * 16) * 2048 + n0 + c];
    T[r + i * 16][c + 0] = v.x; T[r + i * 16][c + 1] = v.y;
    T[r + i * 16][c + 2] = v.z; T[r + i * 16][c + 3] = v.w;
  }
  __syncthreads();
#pragma unroll
  for (int i = 0; i < 4; ++i) {
    int nn = r + i * 16;
    u16x4 o;
    o[0] = f2bf(T[c + 0][nn]); o[1] = f2bf(T[c + 1][nn]);
    o[2] = f2bf(T[c + 2][nn]); o[3] = f2bf(T[c + 3][nn]);
    *(u16x4*)&O[(size_t)(n0 + nn) * 2048 + k0 + c] = o;
  }
}

// ---------------- transpose V: (bh, n, dk) -> Vt (bh, dk, n) ----------------
__global__ __launch_bounds__(256) void transV_kernel(const u16* __restrict__ V,
                                                     u16* __restrict__ Vt) {
  int bh = blockIdx.y;
  int n0 = blockIdx.x * 64;
  const u16* Vb = V + (size_t)bh * 262144;
  u16* Ob = Vt + (size_t)bh * 262144;
  __shared__ u16 T[64 * 129];
  int t = threadIdx.x;
#pragma unroll
  for (int j = 0; j < 4; ++j) {
    int p = t + j * 256;  // 1024 chunks of 8 elems
    int r = p >> 4, c = (p & 15) * 8;
    short8 v = *(const short8*)(Vb + (size_t)(n0 + r) * 128 + c);
#pragma unroll
    for (int e = 0; e < 8; ++e) T[r * 129 + c + e] = (u16)v[e];
  }
  __syncthreads();
#pragma unroll
  for (int pass = 0; pass < 4; ++pass) {
    int dk = (t >> 3) + pass * 32;
    int cn = (t & 7) * 8;
    short8 o;
#pragma unroll
    for (int e = 0; e < 8; ++e) o[e] = (short)T[(cn + e) * 129 + dk];
    *(short8*)(Ob + (size_t)dk * 2048 + n0 + cn) = o;
  }
}

// ---------------- GEMM: C(4096x2048) = A(4096x2048) * WT^T + bias ----------------
template <int MODE>
__global__ __launch_bounds__(256, 2) void gemm128_kernel(
    const u16* __restrict__ A,
    const u16* __restrict__ W0, const u16* __restrict__ W1, const u16* __restrict__ W2,
    const float* __restrict__ b0, const float* __restrict__ b1, const float* __restrict__ b2,
    u16* __restrict__ oq, u16* __restrict__ ok, u16* __restrict__ ov,
    float* __restrict__ of) {
  const u16* W;
  const float* bias;
  u16* outb = nullptr;
  if (MODE == 0) {
    int z = blockIdx.z;
    W = (z == 0) ? W0 : (z == 1) ? W1 : W2;
    bias = (z == 0) ? b0 : (z == 1) ? b1 : b2;
    outb = (z == 0) ? oq : (z == 1) ? ok : ov;
  } else {
    W = W0;
    bias = b0;
  }

  __shared__ __align__(16) u16 As[128 * 32];
  __shared__ __align__(16) u16 Bs[128 * 32];

  int t = threadIdx.x;
  int lane = t & 63, w = t >> 6;
  int wm = w >> 1, wn = w & 1;
  int g = lane >> 4, lr = lane & 15;
  int m0 = blockIdx.y * 128, n0 = blockIdx.x * 128;

  f32x4 acc[4][4] = {};

  for (int kt = 0; kt < 2048; kt += 32) {
#pragma unroll
    for (int rr = 0; rr < 2; ++rr) {
      int p = t + rr * 256;
      int row = p >> 2;
      int cs = (p & 3) ^ (row & 3);
      async_copy16(A + (size_t)(m0 + row) * 2048 + kt + cs * 8, (void*)(As + p * 8));
      async_copy16(W + (size_t)(n0 + row) * 2048 + kt + cs * 8, (void*)(Bs + p * 8));
    }
    __syncthreads();

    short8 af[4], bf[4];
#pragma unroll
    for (int mf = 0; mf < 4; ++mf) {
      int row = wm * 64 + mf * 16 + lr;
      int kc = g ^ (row & 3);
      af[mf] = *(const short8*)&As[row * 32 + kc * 8];
    }
#pragma unroll
    for (int nf = 0; nf < 4; ++nf) {
      int row = wn * 64 + nf * 16 + lr;
      int kc = g ^ (row & 3);
      bf[nf] = *(const short8*)&Bs[row * 32 + kc * 8];
    }
#pragma unroll
    for (int mf = 0; mf < 4; ++mf)
#pragma unroll
      for (int nf = 0; nf < 4; ++nf)
        acc[mf][nf] = __builtin_amdgcn_mfma_f32_16x16x32_bf16(af[mf], bf[nf], acc[mf][nf], 0, 0, 0);
    __syncthreads();
  }

#pragma unroll
  for (int mf = 0; mf < 4; ++mf) {
#pragma unroll
    for (int nf = 0; nf < 4; ++nf) {
      int col = n0 + wn * 64 + nf * 16 + lr;
      float bv = bias[col];
#pragma unroll
      for (int i = 0; i < 4; ++i) {
        int rr = m0 + wm * 64 + mf * 16 + 4 * g + i;
        float v = acc[mf][nf][i] + bv;
        if (MODE == 0) {
          int b = rr >> 11, np = rr & 2047, h = col >> 7, dk = col & 127;
          outb[((size_t)(b * 16 + h) * 2048 + np) * 128 + dk] = f2bf(v);
        } else {
          of[(size_t)rr * 2048 + col] = v;
        }
      }
    }
  }
}

// ---------------- causal flash attention ----------------
// QBLK=128 (8 waves x 16 q-rows), KVBLK=64. grid: (16 q-tiles reversed, 32 bh).
__global__ __launch_bounds__(512, 4) void attn_kernel(
    const u16* __restrict__ Q, const u16* __restrict__ K, const u16* __restrict__ Vt,
    u16* __restrict__ ctx) {
  int bh = blockIdx.y;
  int q0 = (int)(gridDim.x - 1 - blockIdx.x) * 128;
  int t = threadIdx.x, lane = t & 63, w = t >> 6;
  int g = lane >> 4, lr = lane & 15;

  const u16* Qb = Q + (size_t)bh * 262144;
  const u16* Kb = K + (size_t)bh * 262144;
  const u16* Vb = Vt + (size_t)bh * 262144;  // [128 dk][2048 n]

  __shared__ __align__(16) u16 Ks[64 * 128];   // [kv][dk], chunk^=(row&7)
  __shared__ __align__(16) u16 Vs[128 * 64];   // [dk][kv], chunk^=(row&7)
  __shared__ __align__(16) u16 Ps[8 * 16 * 68];

  // hoist Q fragments (16 q-rows per wave)
  int qrow = q0 + w * 16 + lr;
  short8 qf[4];
#pragma unroll
  for (int kb = 0; kb < 4; ++kb)
    qf[kb] = *(const short8*)(Qb + (size_t)qrow * 128 + kb * 32 + g * 8);

  float m2[4], lsum[4];
  f32x4 acc[8] = {};
#pragma unroll
  for (int i = 0; i < 4; ++i) { m2[i] = -1e30f; lsum[i] = 0.f; }

  int wave_max = q0 + w * 16 + 15;
  int kv_end = q0 + 128;

  for (int kv0 = 0; kv0 < kv_end; kv0 += 64) {
    // stage K: 64 rows x 16 chunks, pre-swizzled source
#pragma unroll
    for (int rr = 0; rr < 2; ++rr) {
      int p = t + rr * 512;
      int row = p >> 4;
      int cs = (p & 15) ^ (row & 7);
      async_copy16(Kb + (size_t)(kv0 + row) * 128 + cs * 8, (void*)(Ks + p * 8));
    }
    // stage V^T: 128 dk-rows x 8 chunks, pre-swizzled source
#pragma unroll
    for (int rr = 0; rr < 2; ++rr) {
      int p = t + rr * 512;
      int row = p >> 3;
      int cs = (p & 7) ^ (row & 7);
      async_copy16(Vb + (size_t)row * 2048 + kv0 + cs * 8, (void*)(Vs + p * 8));
    }
    __syncthreads();

    if (kv0 <= wave_max) {  // wave-uniform causal skip
      // QK^T: 4 kv sub-tiles x 4 dk chunks
      f32x4 sf[4] = {};
#pragma unroll
      for (int sb = 0; sb < 4; ++sb) {
#pragma unroll
        for (int kb = 0; kb < 4; ++kb) {
          int krow = 16 * sb + lr;
          int cc = (kb * 4 + g) ^ (krow & 7);
          short8 kf = *(const short8*)&Ks[krow * 128 + cc * 8];
          sf[sb] = __builtin_amdgcn_mfma_f32_16x16x32_bf16(qf[kb], kf, sf[sb], 0, 0, 0);
        }
      }

      // online softmax (exp2 domain), 4 q-rows per lane
      u16* Pw = Ps + w * 16 * 68;
#pragma unroll
      for (int i = 0; i < 4; ++i) {
        int row = q0 + w * 16 + 4 * g + i;
        float s[4];
#pragma unroll
        for (int sb = 0; sb < 4; ++sb) {
          s[sb] = sf[sb][i] * QK_SCALE;
          if (kv0 + 16 * sb + lr > row) s[sb] = -1e30f;
        }
        float tmax = fmaxf(fmaxf(s[0], s[1]), fmaxf(s[2], s[3]));
        tmax = fmaxf(tmax, __shfl_xor(tmax, 1));
        tmax = fmaxf(tmax, __shfl_xor(tmax, 2));
        tmax = fmaxf(tmax, __shfl_xor(tmax, 4));
        tmax = fmaxf(tmax, __shfl_xor(tmax, 8));
        float mn = fmaxf(m2[i], tmax);
        float r = exp2f(m2[i] - mn);
        m2[i] = mn;
        float p0 = exp2f(s[0] - mn), p1 = exp2f(s[1] - mn);
        float p2 = exp2f(s[2] - mn), p3 = exp2f(s[3] - mn);
        float rs = (p0 + p1) + (p2 + p3);
        rs += __shfl_xor(rs, 1);
        rs += __shfl_xor(rs, 2);
        rs += __shfl_xor(rs, 4);
        rs += __shfl_xor(rs, 8);
        lsum[i] = lsum[i] * r + rs;
#pragma unroll
        for (int nb = 0; nb < 8; ++nb) acc[nb][i] *= r;
        int rbase = (4 * g + i) * 68;
        Pw[rbase + lr] = f2bf(p0);
        Pw[rbase + 16 + lr] = f2bf(p1);
        Pw[rbase + 32 + lr] = f2bf(p2);
        Pw[rbase + 48 + lr] = f2bf(p3);
      }

      // P fragments (A-operand): row lr, k-chunks
      short8 pf0 = *(const short8*)&Pw[lr * 68 + g * 8];
      short8 pf1 = *(const short8*)&Pw[lr * 68 + 32 + g * 8];

      // PV: 8 dk chunks x 2 kv-32 chunks
#pragma unroll
      for (int nb = 0; nb < 8; ++nb) {
        int vrow = nb * 16 + lr;
        int c0 = g ^ (vrow & 7);
        int c1 = (4 + g) ^ (vrow & 7);
        short8 vf0 = *(const short8*)&Vs[vrow * 64 + c0 * 8];
        short8 vf1 = *(const short8*)&Vs[vrow * 64 + c1 * 8];
        acc[nb] = __builtin_amdgcn_mfma_f32_16x16x32_bf16(pf0, vf0, acc[nb], 0, 0, 0);
        acc[nb] = __builtin_amdgcn_mfma_f32_16x16x32_bf16(pf1, vf1, acc[nb], 0, 0, 0);
      }
    }
    __syncthreads();
  }

  // epilogue: normalize, store ctx (b, n, d) bf16
  int b = bh >> 4, h = bh & 15;
#pragma unroll
  for (int i = 0; i < 4; ++i) {
    int row = q0 + w * 16 + 4 * g + i;
    float inv = 1.f / lsum[i];
    u16* dst = ctx + ((size_t)(b * 2048 + row)) * 2048 + h * 128;
#pragma unroll
    for (int nb = 0; nb < 8; ++nb) dst[16 * nb + lr] = f2bf(acc[nb][i] * inv);
  }
}

// ---------------- launcher ----------------
extern "C" void kernel_launch(void* const* d_in, const int* in_sizes, int n_in,
                              void* d_out, int out_size, void* d_ws, size_t ws_size,
                              hipStream_t stream) {
  const float* x = (const float*)d_in[0];
  const float* Wq = (const float*)d_in[1];
  const float* bq = (const float*)d_in[2];
  const float* Wk = (const float*)d_in[3];
  const float* bk = (const float*)d_in[4];
  const float* Wv = (const float*)d_in[5];
  const float* bv = (const float*)d_in[6];
  const float* Wo = (const float*)d_in[7];
  const float* bo = (const float*)d_in[8];
  float* out = (float*)d_out;

  u16* xb = (u16*)d_ws;               // 4096x2048 bf16 (dead after gemm<0>)
  u16* WTq = xb + 8388608;
  u16* WTk = WTq + 4194304;
  u16* WTv = WTk + 4194304;
  u16* WTo = WTv + 4194304;
  u16* Qs = WTo + 4194304;            // (b,h,n,dk)
  u16* Ks = Qs + 8388608;
  u16* Vs = Ks + 8388608;
  u16* ctx = Vs + 8388608;            // (b,n,d)
  u16* Vt = xb;                       // alias: (b,h,dk,n), written after xb is dead

  cast_x_kernel<<<4096, 256, 0, stream>>>(x, xb, 8388608);
  transW_kernel<<<dim3(32, 32, 4), 256, 0, stream>>>(Wq, Wk, Wv, Wo, WTq, WTk, WTv, WTo);
  gemm128_kernel<0><<<dim3(16, 32, 3), 256, 0, stream>>>(
      xb, WTq, WTk, WTv, bq, bk, bv, Qs, Ks, Vs, nullptr);
  transV_kernel<<<dim3(32, 32), 256, 0, stream>>>(Vs, Vt);
  attn_kernel<<<dim3(16, 32), 512, 0, stream>>>(Qs, Ks, Vt, ctx);
  gemm128_kernel<1><<<dim3(16, 32, 1), 256, 0, stream>>>(
      ctx, WTo, nullptr, nullptr, bo, nullptr, nullptr, nullptr, nullptr, nullptr, out);
}

// Round 3
// 293.261 us; speedup vs baseline: 1.7006x; 1.2551x over previous
//
#include <hip/hip_runtime.h>

typedef unsigned short u16;
typedef unsigned int u32;
typedef __attribute__((ext_vector_type(8))) short short8;
typedef __attribute__((ext_vector_type(4))) float f32x4;
typedef __attribute__((ext_vector_type(16))) float f32x16;
typedef __attribute__((ext_vector_type(4))) u16 u16x4;
typedef __attribute__((ext_vector_type(4))) u32 u32x4;

#define QK_SCALE 0.12751736915185197f  // log2(e)/sqrt(128)

__device__ __forceinline__ u16 f2bf(float f) {
  u32 u = __builtin_bit_cast(u32, f);
  u = u + 0x7FFFu + ((u >> 16) & 1u);
  return (u16)(u >> 16);
}

__device__ __forceinline__ void async_copy16(const void* g, void* l) {
  __builtin_amdgcn_global_load_lds(
      (const __attribute__((address_space(1))) u32*)g,
      (__attribute__((address_space(3))) u32*)l, 16, 0, 0);
}

// ---------------- cast x (fp32 -> bf16) ----------------
__global__ __launch_bounds__(256) void cast_x_kernel(const float* __restrict__ x,
                                                     u16* __restrict__ xb, int n) {
  int i = (blockIdx.x * 256 + threadIdx.x) * 8;
  if (i >= n) return;
  float4 a = *(const float4*)(x + i);
  float4 b = *(const float4*)(x + i + 4);
  short8 o;
  o[0] = (short)f2bf(a.x); o[1] = (short)f2bf(a.y);
  o[2] = (short)f2bf(a.z); o[3] = (short)f2bf(a.w);
  o[4] = (short)f2bf(b.x); o[5] = (short)f2bf(b.y);
  o[6] = (short)f2bf(b.z); o[7] = (short)f2bf(b.w);
  *(short8*)(xb + i) = o;
}

// ---------------- transpose+cast W (fp32 [k][n] -> bf16 WT [n][k]) ----------------
__global__ __launch_bounds__(256) void transW_kernel(
    const float* __restrict__ W0, const float* __restrict__ W1,
    const float* __restrict__ W2, const float* __restrict__ W3,
    u16* __restrict__ O0, u16* __restrict__ O1, u16* __restrict__ O2, u16* __restrict__ O3) {
  const float* Ws[4] = {W0, W1, W2, W3};
  u16* Os[4] = {O0, O1, O2, O3};
  const float* W = Ws[blockIdx.z];
  u16* O = Os[blockIdx.z];

  __shared__ float T[64][65];
  int t = threadIdx.x;
  int k0 = blockIdx.y * 64, n0 = blockIdx.x * 64;
  int r = t >> 4, c = (t & 15) * 4;
#pragma unroll
  for (int i = 0; i < 4; ++i) {
    float4 v = *(const float4*)&W[(size_t)(k0 + r + i * 16) * 2048 + n0 + c];
    T[r + i * 16][c + 0] = v.x; T[r + i * 16][c + 1] = v.y;
    T[r + i * 16][c + 2] = v.z; T[r + i * 16][c + 3] = v.w;
  }
  __syncthreads();
#pragma unroll
  for (int i = 0; i < 4; ++i) {
    int nn = r + i * 16;
    u16x4 o;
    o[0] = f2bf(T[c + 0][nn]); o[1] = f2bf(T[c + 1][nn]);
    o[2] = f2bf(T[c + 2][nn]); o[3] = f2bf(T[c + 3][nn]);
    *(u16x4*)&O[(size_t)(n0 + nn) * 2048 + k0 + c] = o;
  }
}

// ---------------- transpose V: (bh, n, dk) -> Vt (bh, dk, n) ----------------
__global__ __launch_bounds__(256) void transV_kernel(const u16* __restrict__ V,
                                                     u16* __restrict__ Vt) {
  int bh = blockIdx.y;
  int n0 = blockIdx.x * 64;
  const u16* Vb = V + (size_t)bh * 262144;
  u16* Ob = Vt + (size_t)bh * 262144;
  __shared__ u16 T[64 * 129];
  int t = threadIdx.x;
#pragma unroll
  for (int j = 0; j < 4; ++j) {
    int p = t + j * 256;  // 1024 chunks of 8 elems
    int r = p >> 4, c = (p & 15) * 8;
    short8 v = *(const short8*)(Vb + (size_t)(n0 + r) * 128 + c);
#pragma unroll
    for (int e = 0; e < 8; ++e) T[r * 129 + c + e] = (u16)v[e];
  }
  __syncthreads();
#pragma unroll
  for (int pass = 0; pass < 4; ++pass) {
    int dk = (t >> 3) + pass * 32;
    int cn = (t & 7) * 8;
    short8 o;
#pragma unroll
    for (int e = 0; e < 8; ++e) o[e] = (short)T[(cn + e) * 129 + dk];
    *(short8*)(Ob + (size_t)dk * 2048 + n0 + cn) = o;
  }
}

// ---------------- GEMM: C(4096x2048) = A(4096x2048) * WT^T + bias ----------------
template <int MODE>
__global__ __launch_bounds__(256, 2) void gemm128_kernel(
    const u16* __restrict__ A,
    const u16* __restrict__ W0, const u16* __restrict__ W1, const u16* __restrict__ W2,
    const float* __restrict__ b0, const float* __restrict__ b1, const float* __restrict__ b2,
    u16* __restrict__ oq, u16* __restrict__ ok, u16* __restrict__ ov,
    float* __restrict__ of) {
  const u16* W;
  const float* bias;
  u16* outb = nullptr;
  if (MODE == 0) {
    int z = blockIdx.z;
    W = (z == 0) ? W0 : (z == 1) ? W1 : W2;
    bias = (z == 0) ? b0 : (z == 1) ? b1 : b2;
    outb = (z == 0) ? oq : (z == 1) ? ok : ov;
  } else {
    W = W0;
    bias = b0;
  }

  __shared__ __align__(16) u16 As[128 * 32];
  __shared__ __align__(16) u16 Bs[128 * 32];

  int t = threadIdx.x;
  int lane = t & 63, w = t >> 6;
  int wm = w >> 1, wn = w & 1;
  int g = lane >> 4, lr = lane & 15;
  int m0 = blockIdx.y * 128, n0 = blockIdx.x * 128;

  f32x4 acc[4][4] = {};

  for (int kt = 0; kt < 2048; kt += 32) {
#pragma unroll
    for (int rr = 0; rr < 2; ++rr) {
      int p = t + rr * 256;
      int row = p >> 2;
      int cs = (p & 3) ^ (row & 3);
      async_copy16(A + (size_t)(m0 + row) * 2048 + kt + cs * 8, (void*)(As + p * 8));
      async_copy16(W + (size_t)(n0 + row) * 2048 + kt + cs * 8, (void*)(Bs + p * 8));
    }
    __syncthreads();

    short8 af[4], bf[4];
#pragma unroll
    for (int mf = 0; mf < 4; ++mf) {
      int row = wm * 64 + mf * 16 + lr;
      int kc = g ^ (row & 3);
      af[mf] = *(const short8*)&As[row * 32 + kc * 8];
    }
#pragma unroll
    for (int nf = 0; nf < 4; ++nf) {
      int row = wn * 64 + nf * 16 + lr;
      int kc = g ^ (row & 3);
      bf[nf] = *(const short8*)&Bs[row * 32 + kc * 8];
    }
#pragma unroll
    for (int mf = 0; mf < 4; ++mf)
#pragma unroll
      for (int nf = 0; nf < 4; ++nf)
        acc[mf][nf] = __builtin_amdgcn_mfma_f32_16x16x32_bf16(af[mf], bf[nf], acc[mf][nf], 0, 0, 0);
    __syncthreads();
  }

#pragma unroll
  for (int mf = 0; mf < 4; ++mf) {
#pragma unroll
    for (int nf = 0; nf < 4; ++nf) {
      int col = n0 + wn * 64 + nf * 16 + lr;
      float bv = bias[col];
#pragma unroll
      for (int i = 0; i < 4; ++i) {
        int rr = m0 + wm * 64 + mf * 16 + 4 * g + i;
        float v = acc[mf][nf][i] + bv;
        if (MODE == 0) {
          int b = rr >> 11, np = rr & 2047, h = col >> 7, dk = col & 127;
          outb[((size_t)(b * 16 + h) * 2048 + np) * 128 + dk] = f2bf(v);
        } else {
          of[(size_t)rr * 2048 + col] = v;
        }
      }
    }
  }
}

// ---------------- causal flash attention (32x32 MFMA, swapped QK^T) ----------------
// 4 waves x 32 q-rows (QBLK=128), KVBLK=64. grid: (16 q-tiles reversed, 32 bh), 256 thr.
// Per lane: q = q0w + (lane&31); h = lane>>5.
// S^T = mfma(A=K, B=Q): D col=q, row(kv-slot) = (reg&3)+8*(reg>>2)+4h.
// O^T = mfma(A=V^T, B=P^T): D col=q, row(dk-slot) = same formula.
__global__ __launch_bounds__(256, 2) void attn_kernel(
    const u16* __restrict__ Q, const u16* __restrict__ K, const u16* __restrict__ Vt,
    u16* __restrict__ ctx) {
  int bh = blockIdx.y;
  int q0 = (int)(gridDim.x - 1 - blockIdx.x) * 128;
  int t = threadIdx.x, lane = t & 63, w = t >> 6;
  int h = lane >> 5;
  int ql = lane & 31;
  int q0w = q0 + w * 32;
  int qg = q0w + ql;

  const u16* Qb = Q + (size_t)bh * 262144;
  const u16* Kb = K + (size_t)bh * 262144;
  const u16* Vb = Vt + (size_t)bh * 262144;  // [128 dk][2048 n]

  // 64KB: two 32KB buffers; each = K[64][128] + pair-packed V^T[64][128]
  __shared__ __align__(16) u16 SM[32768];

  // hoist Q fragments: qf[kk][j] = Q[qg][16kk + 8h + j]
  short8 qf[8];
  {
    const u16* qrow = Qb + (size_t)qg * 128 + 8 * h;
#pragma unroll
    for (int kk = 0; kk < 8; ++kk) qf[kk] = *(const short8*)(qrow + 16 * kk);
  }

  f32x16 acc[4] = {};  // O^T: acc[d] -> dk = 32d + slot(reg,h), col q = ql
  float m = -1e30f, lsum = 0.f;

  int nt = (q0 + 128) >> 6;
  int wave_max = q0w + 31;

  // STAGE: K 1024 chunks + V 1024 chunks; LDS linear dest, pre-swizzled src
  auto STAGE = [&](int buf, int kv0) {
    u16* Ksb = SM + buf * 16384;
    u16* Vsb = Ksb + 8192;
#pragma unroll
    for (int it = 0; it < 4; ++it) {
      int p = t + 256 * it;
      int row = p >> 4;
      int c = (p & 15) ^ (row & 15);
      async_copy16(Kb + (size_t)(kv0 + row) * 128 + c * 8, (void*)(Ksb + p * 8));
      // pair-packed V^T: physical row r holds dk=2r (cols 0..63) and dk=2r+1 (cols 64..127)
      async_copy16(Vb + (size_t)(2 * row + (c >> 3)) * 2048 + kv0 + (c & 7) * 8,
                   (void*)(Vsb + p * 8));
    }
  };

  STAGE(0, 0);
  __syncthreads();

  for (int step = 0; step < nt; ++step) {
    int kv0 = step << 6;
    int cur = step & 1;
    if (step + 1 < nt) STAGE(cur ^ 1, (step + 1) << 6);

    if (kv0 <= wave_max) {
      const u16* Ksb = SM + cur * 16384;
      const u16* Vsb = Ksb + 8192;

      // ---- QK^T ----
      f32x16 s0 = {}, s1 = {};
#pragma unroll
      for (int kk = 0; kk < 8; ++kk) {
        int c = (2 * kk + h) ^ (ql & 15);
        short8 kf0 = *(const short8*)&Ksb[ql * 128 + c * 8];
        s0 = __builtin_amdgcn_mfma_f32_32x32x16_bf16(kf0, qf[kk], s0, 0, 0, 0);
        short8 kf1 = *(const short8*)&Ksb[(32 + ql) * 128 + c * 8];
        s1 = __builtin_amdgcn_mfma_f32_32x32x16_bf16(kf1, qf[kk], s1, 0, 0, 0);
      }

      // ---- mask (only needed near diagonal) ----
      if (kv0 + 63 > q0w) {
#pragma unroll
        for (int r = 0; r < 16; ++r) {
          int slot = (r & 3) + 8 * (r >> 2) + 4 * h;
          if (kv0 + slot > qg) s0[r] = -1e30f;
          if (kv0 + 32 + slot > qg) s1[r] = -1e30f;
        }
      }

      // ---- row max (own 32 + partner via lane^32) ----
      float tm = fmaxf(s0[0], s1[0]);
#pragma unroll
      for (int r = 1; r < 16; ++r) tm = fmaxf(tm, fmaxf(s0[r], s1[r]));
      tm = fmaxf(tm, __shfl_xor(tm, 32));
      tm *= QK_SCALE;

      // ---- defer-max rescale (T13) ----
      if (__any(tm > m + 8.0f)) {
        float mn = fmaxf(m, tm);
        float rr = exp2f(m - mn);
        m = mn;
        lsum *= rr;
#pragma unroll
        for (int d = 0; d < 4; ++d)
#pragma unroll
          for (int i = 0; i < 16; ++i) acc[d][i] *= rr;
      }

      // ---- p = exp2(s*scale - m), row sum ----
      float rs = 0.f;
#pragma unroll
      for (int r = 0; r < 16; ++r) {
        s0[r] = exp2f(fmaf(s0[r], QK_SCALE, -m));
        s1[r] = exp2f(fmaf(s1[r], QK_SCALE, -m));
        rs += s0[r] + s1[r];
      }
      rs += __shfl_xor(rs, 32);
      lsum += rs;

      // ---- pack P to bf16 pairs ----
      u32 up0[8], up1[8];
#pragma unroll
      for (int mi = 0; mi < 8; ++mi) {
        asm("v_cvt_pk_bf16_f32 %0, %1, %2" : "=v"(up0[mi]) : "v"(s0[2 * mi]), "v"(s0[2 * mi + 1]));
        asm("v_cvt_pk_bf16_f32 %0, %1, %2" : "=v"(up1[mi]) : "v"(s1[2 * mi]), "v"(s1[2 * mi + 1]));
      }

      // ---- exchange halves + PV ----
#pragma unroll
      for (int g16 = 0; g16 < 4; ++g16) {
        int Qd = g16 & 1;
        u32 c0 = (g16 < 2) ? up0[4 * Qd + 0] : up1[4 * Qd + 0];
        u32 c1 = (g16 < 2) ? up0[4 * Qd + 1] : up1[4 * Qd + 1];
        u32 c2 = (g16 < 2) ? up0[4 * Qd + 2] : up1[4 * Qd + 2];
        u32 c3 = (g16 < 2) ? up0[4 * Qd + 3] : up1[4 * Qd + 3];
        u32 d0 = __shfl_xor(c0, 32), d1 = __shfl_xor(c1, 32);
        u32 d2 = __shfl_xor(c2, 32), d3 = __shfl_xor(c3, 32);
        u32x4 paw;
        paw[0] = h ? d2 : c0;
        paw[1] = h ? d3 : c1;
        paw[2] = h ? c2 : d0;
        paw[3] = h ? c3 : d1;
        short8 pa = __builtin_bit_cast(short8, paw);
#pragma unroll
        for (int d = 0; d < 4; ++d) {
          int dk = 32 * d + ql;
          int prow = dk >> 1;
          int lch = (dk & 1) * 8 + 2 * g16 + h;
          int slot = lch ^ (prow & 15);
          short8 vf = *(const short8*)&Vsb[prow * 128 + slot * 8];
          acc[d] = __builtin_amdgcn_mfma_f32_32x32x16_bf16(vf, pa, acc[d], 0, 0, 0);
        }
      }
    }
    __syncthreads();
  }

  // ---- epilogue: normalize, transpose via LDS, coalesced store ----
  u16* Ot = SM + w * 4352;  // [32 q][136 pad] u16
  float inv = 1.f / lsum;
#pragma unroll
  for (int d = 0; d < 4; ++d)
#pragma unroll
    for (int r = 0; r < 16; ++r) {
      int dk = 32 * d + (r & 3) + 8 * (r >> 2) + 4 * h;
      Ot[ql * 136 + dk] = f2bf(acc[d][r] * inv);
    }
  __syncthreads();
  int b = bh >> 4, hh = bh & 15;
#pragma unroll
  for (int it = 0; it < 8; ++it) {
    int p = lane + 64 * it;
    int row = p >> 4, ch = p & 15;
    short8 v = *(const short8*)&Ot[row * 136 + ch * 8];
    *(short8*)(ctx + ((size_t)(b * 2048 + q0 + w * 32 + row)) * 2048 + hh * 128 + ch * 8) = v;
  }
}

// ---------------- launcher ----------------
extern "C" void kernel_launch(void* const* d_in, const int* in_sizes, int n_in,
                              void* d_out, int out_size, void* d_ws, size_t ws_size,
                              hipStream_t stream) {
  const float* x = (const float*)d_in[0];
  const float* Wq = (const float*)d_in[1];
  const float* bq = (const float*)d_in[2];
  const float* Wk = (const float*)d_in[3];
  const float* bk = (const float*)d_in[4];
  const float* Wv = (const float*)d_in[5];
  const float* bv = (const float*)d_in[6];
  const float* Wo = (const float*)d_in[7];
  const float* bo = (const float*)d_in[8];
  float* out = (float*)d_out;

  u16* xb = (u16*)d_ws;               // 4096x2048 bf16 (dead after gemm<0>)
  u16* WTq = xb + 8388608;
  u16* WTk = WTq + 4194304;
  u16* WTv = WTk + 4194304;
  u16* WTo = WTv + 4194304;
  u16* Qs = WTo + 4194304;            // (b,h,n,dk)
  u16* Ks = Qs + 8388608;
  u16* Vs = Ks + 8388608;
  u16* ctx = Vs + 8388608;            // (b,n,d)
  u16* Vt = xb;                       // alias: (b,h,dk,n), written after xb is dead

  cast_x_kernel<<<4096, 256, 0, stream>>>(x, xb, 8388608);
  transW_kernel<<<dim3(32, 32, 4), 256, 0, stream>>>(Wq, Wk, Wv, Wo, WTq, WTk, WTv, WTo);
  gemm128_kernel<0><<<dim3(16, 32, 3), 256, 0, stream>>>(
      xb, WTq, WTk, WTv, bq, bk, bv, Qs, Ks, Vs, nullptr);
  transV_kernel<<<dim3(32, 32), 256, 0, stream>>>(Vs, Vt);
  attn_kernel<<<dim3(16, 32), 256, 0, stream>>>(Qs, Ks, Vt, ctx);
  gemm128_kernel<1><<<dim3(16, 32, 1), 256, 0, stream>>>(
      ctx, WTo, nullptr, nullptr, bo, nullptr, nullptr, nullptr, nullptr, nullptr, out);
}